// Round 13
// baseline (29.167 us; speedup 1.0000x reference)
//
#include <hip/hip_runtime.h>

typedef __attribute__((ext_vector_type(8))) short bf16x8;
typedef __attribute__((ext_vector_type(4))) float f32x4;
typedef __attribute__((ext_vector_type(2))) float f32x2;

union FragU { uint4 q; bf16x8 h; };

// packed f32 -> 2x bf16 (RNE), 1 VALU instr
__device__ __forceinline__ unsigned cvt_pk(float lo, float hi) {
  unsigned r;
  asm("v_cvt_pk_bf16_f32 %0, %1, %2" : "=v"(r) : "v"(lo), "v"(hi));
  return r;
}

// ---------------------------------------------------------------------------
// kX: cast x into MFMA B-fragment layout (r8-proven).
//   xbf unit[((b*16+t)*8+c)*64 + l] = x[b][t*16+(l&15)][c*32+(l>>4)*8 .. +8]
// Grid 512 x 256 = 131072 units, 1/thread.
// ---------------------------------------------------------------------------
__global__ __launch_bounds__(256) void kX(
    const float* __restrict__ x, uint4* __restrict__ xbf)
{
  const int u = blockIdx.x * 256 + threadIdx.x;
  const int l = u & 63, c = (u >> 6) & 7, t = (u >> 9) & 15, b = u >> 13;
  const int fr = l & 15, fq = l >> 4;
  const float* p = x + (size_t)((b * 16 + t) * 16 + fr) * 256 + c * 32 + fq * 8;
  float4 va = *(const float4*)p;
  float4 vb = *(const float4*)(p + 4);
  xbf[u] = make_uint4(cvt_pk(va.x, va.y), cvt_pk(va.z, va.w),
                      cvt_pk(vb.x, vb.y), cvt_pk(vb.z, vb.w));
}

// ---------------------------------------------------------------------------
// kA: block (b, hg) owns batch b, h-range [hg*4, hg*4+4).  512 thr = 8 waves,
// grid (16,32) = 512 blocks -> 2 blocks/CU (the controlled change).
// MFMA n-dim: rows 0-3 = a-cols, 4-7 = c-cols (+b1), 8-15 zero/discard.
// Phase 2: wave (hp=wv&3, kh=wv>>2), R=4 m/lane, broadcast ds_read_b128,
// abs-identity with r11-proven pk_add+fabs inner (1.5 VALU/elem):
//   mh[m,h] = (256*a + sumC + sum_k2 |a+c|) / 512.
// Phase 3: pack mh (4 h = one 8B half-unit) into kB fragment layout.
// ---------------------------------------------------------------------------
__global__ __launch_bounds__(512) void kA(
    const uint4* __restrict__ xbf, const float* __restrict__ W1,
    const float* __restrict__ b1, uint4* __restrict__ mf)
{
  __shared__ float As[4][260];
  __shared__ float Cs[4][260];
  __shared__ float PB[4][260];

  const int tid = threadIdx.x, lane = tid & 63, wv = tid >> 6;  // wv 0..7
  const int b = blockIdx.x, hg = blockIdx.y;                    // hg 0..31
  const int fr = lane & 15, fq = lane >> 4;

  // A-frags: fr<4 -> W1a col hg*4+fr; fr 4..7 -> W1b col hg*4+fr-4; else 0
  FragU afr[8];
  if (fr < 8) {
    const float* __restrict__ wp =
        W1 + (size_t)((fr >= 4) ? 256 : 0) * 128 + hg * 4 + (fr & 3);
#pragma unroll
    for (int c = 0; c < 8; ++c) {
      float v[8];
#pragma unroll
      for (int j = 0; j < 8; ++j) v[j] = wp[(size_t)(c * 32 + fq * 8 + j) * 128];
      afr[c].q = make_uint4(cvt_pk(v[0], v[1]), cvt_pk(v[2], v[3]),
                            cvt_pk(v[4], v[5]), cvt_pk(v[6], v[7]));
    }
  } else {
#pragma unroll
    for (int c = 0; c < 8; ++c) afr[c].q = make_uint4(0u, 0u, 0u, 0u);
  }

  float b1v[4];
#pragma unroll
  for (int g = 0; g < 4; ++g) b1v[g] = b1[hg * 4 + g];  // used by fq==1 lanes

  // ---- phase 1: MFMA; wave wv does m-tiles {wv, wv+8} ----
#pragma unroll
  for (int s = 0; s < 2; ++s) {
    const int t = wv + s * 8;
    f32x4 acc = {0.f, 0.f, 0.f, 0.f};
#pragma unroll
    for (int c = 0; c < 8; ++c) {
      FragU bfr;
      bfr.q = xbf[((size_t)(b * 16 + t) * 8 + c) * 64 + lane];
      acc = __builtin_amdgcn_mfma_f32_16x16x32_bf16(afr[c].h, bfr.h, acc, 0, 0, 0);
    }
    const int m = t * 16 + fr;
    if (fq == 0) {
#pragma unroll
      for (int g = 0; g < 4; ++g) As[g][m] = acc[g];
    } else if (fq == 1) {
#pragma unroll
      for (int g = 0; g < 4; ++g) Cs[g][m] = acc[g] + b1v[g];
    }
  }
  __syncthreads();

  // ---- phase 2: pairwise abs-identity; wave = (hp, kh) ----
  const int hp = wv & 3, kh = wv >> 2;
  const float a0 = As[hp][lane],       a1 = As[hp][64 + lane];
  const float a2 = As[hp][128 + lane], a3 = As[hp][192 + lane];

  float sumC = 0.f;
  if (kh == 0) {
    float4 s4 = *(const float4*)&Cs[hp][lane * 4];
    sumC = (s4.x + s4.y) + (s4.z + s4.w);
#pragma unroll
    for (int off = 32; off >= 1; off >>= 1) sumC += __shfl_xor(sumC, off, 64);
  }

  const f32x2 aa0 = {a0, a0}, aa1 = {a1, a1}, aa2 = {a2, a2}, aa3 = {a3, a3};
  float s0l = 0.f, s0h = 0.f, s1l = 0.f, s1h = 0.f;
  float s2l = 0.f, s2h = 0.f, s3l = 0.f, s3h = 0.f;
  const int u0 = kh * 32;

  // per 2 elems: 1 v_pk_add_f32 + 2 fabs-folded v_add_f32 = 1.5 VALU/elem
  // (r11-proven: compiles, fabs folds as input modifier)
#define PROW(aa, sl, sh)                                                   \
  {                                                                        \
    f32x2 t0, t1;                                                          \
    asm("v_pk_add_f32 %0, %1, %2" : "=v"(t0) : "v"(aa), "v"(c01));         \
    asm("v_pk_add_f32 %0, %1, %2" : "=v"(t1) : "v"(aa), "v"(c23));         \
    sl += __builtin_fabsf(t0.x); sh += __builtin_fabsf(t0.y);              \
    sl += __builtin_fabsf(t1.x); sh += __builtin_fabsf(t1.y);              \
  }

#pragma unroll 8
  for (int u = 0; u < 32; ++u) {
    float4 c4 = *(const float4*)&Cs[hp][(u0 + u) * 4];  // uniform -> broadcast
    f32x2 c01 = {c4.x, c4.y}, c23 = {c4.z, c4.w};
    PROW(aa0, s0l, s0h)
    PROW(aa1, s1l, s1h)
    PROW(aa2, s2l, s2h)
    PROW(aa3, s3l, s3h)
  }
#undef PROW

  if (kh == 1) {
    PB[hp][lane]       = s0l + s0h;
    PB[hp][64 + lane]  = s1l + s1h;
    PB[hp][128 + lane] = s2l + s2h;
    PB[hp][192 + lane] = s3l + s3h;
  }
  __syncthreads();

  if (kh == 0) {  // combine: (256a + sumC + abs_half0 + abs_half1) / 512
    As[hp][lane]       = (256.f * a0 + sumC + (s0l + s0h) + PB[hp][lane])       * (1.f / 512.f);
    As[hp][64 + lane]  = (256.f * a1 + sumC + (s1l + s1h) + PB[hp][64 + lane])  * (1.f / 512.f);
    As[hp][128 + lane] = (256.f * a2 + sumC + (s2l + s2h) + PB[hp][128 + lane]) * (1.f / 512.f);
    As[hp][192 + lane] = (256.f * a3 + sumC + (s3l + s3h) + PB[hp][192 + lane]) * (1.f / 512.f);
  }
  __syncthreads();

  // ---- phase 3: pack 4 h-values of row m=tid as one 8B half-unit ----
  if (tid < 256) {
    const int m = tid, T = m >> 4, fr2 = m & 15;
    const int cc = hg >> 3;            // k-chunk of these 4 h
    const int fq2 = (hg & 7) >> 1;     // fragment quarter (8 k each)
    const size_t unit = ((size_t)(b * 16 + T) * 4 + cc) * 64 + fq2 * 16 + fr2;
    unsigned* mfd = (unsigned*)mf;
    uint2 o = make_uint2(cvt_pk(As[0][m], As[1][m]), cvt_pk(As[2][m], As[3][m]));
    *(uint2*)&mfd[unit * 4 + (hg & 1) * 2] = o;
  }
}

// ---------------------------------------------------------------------------
// kB: out[m][d] = mh[m,:]@W2[:,d] + b2[d] + x[m][d].  A = mf fragments,
// B gather-cast from native W2 f32 (r11-proven). Grid (256,4) x 256 thr.
// ---------------------------------------------------------------------------
__global__ __launch_bounds__(256) void kB(
    const uint4* __restrict__ mf, const float* __restrict__ W2,
    const float* __restrict__ b2, const float* __restrict__ x,
    float* __restrict__ out)
{
  const int tid = threadIdx.x, lane = tid & 63, wu = tid >> 6;
  const int mt = blockIdx.x;             // 0..255
  const int dg = blockIdx.y * 4 + wu;    // 0..15
  const int fr = lane & 15, fq = lane >> 4;

  const float* __restrict__ w2p = W2 + dg * 16 + fr;
  FragU bfr[4];
#pragma unroll
  for (int c = 0; c < 4; ++c) {
    float v[8];
#pragma unroll
    for (int j = 0; j < 8; ++j) v[j] = w2p[(size_t)(c * 32 + fq * 8 + j) * 256];
    bfr[c].q = make_uint4(cvt_pk(v[0], v[1]), cvt_pk(v[2], v[3]),
                          cvt_pk(v[4], v[5]), cvt_pk(v[6], v[7]));
  }

  f32x4 acc = {0.f, 0.f, 0.f, 0.f};
#pragma unroll
  for (int c = 0; c < 4; ++c) {
    FragU a;
    a.q = mf[((size_t)mt * 4 + c) * 64 + lane];
    acc = __builtin_amdgcn_mfma_f32_16x16x32_bf16(a.h, bfr[c].h, acc, 0, 0, 0);
  }

  const int d = dg * 16 + fr;
  const float bv = b2[d];
#pragma unroll
  for (int g = 0; g < 4; ++g) {
    const int m = mt * 16 + fq * 4 + g;
    const size_t o = (size_t)m * 256 + d;
    out[o] = acc[g] + bv + x[o];
  }
}

extern "C" void kernel_launch(void* const* d_in, const int* in_sizes, int n_in,
                              void* d_out, int out_size, void* d_ws, size_t ws_size,
                              hipStream_t stream) {
  const float* x  = (const float*)d_in[0];
  const float* W1 = (const float*)d_in[1];
  const float* b1 = (const float*)d_in[2];
  const float* W2 = (const float*)d_in[3];
  const float* b2 = (const float*)d_in[4];
  float* out = (float*)d_out;

  char* ws = (char*)d_ws;
  uint4* xbf = (uint4*)ws;                 // 131072 units = 2 MB
  uint4* mf  = (uint4*)(ws + (2u << 20));  // 65536 units = 1 MB

  kX<<<512, 256, 0, stream>>>(x, xbf);
  kA<<<dim3(16, 32), 512, 0, stream>>>(xbf, W1, b1, mf);
  kB<<<dim3(256, 4), 256, 0, stream>>>(mf, W2, b2, x, out);
}

// Round 14
// 25.696 us; speedup vs baseline: 1.1351x; 1.1351x over previous
//
#include <hip/hip_runtime.h>

typedef __attribute__((ext_vector_type(8))) short bf16x8;
typedef __attribute__((ext_vector_type(4))) float f32x4;
typedef __attribute__((ext_vector_type(2))) float f32x2;

union FragU { uint4 q; bf16x8 h; };

__device__ __forceinline__ unsigned short f2bf(float f) {
  unsigned u = __float_as_uint(f);
  u += 0x7FFFu + ((u >> 16) & 1u);   // RNE
  return (unsigned short)(u >> 16);
}
__device__ __forceinline__ unsigned pack2(float lo, float hi) {
  return (unsigned)f2bf(lo) | ((unsigned)f2bf(hi) << 16);
}

// ---------------------------------------------------------------------------
// kX (r8-verbatim): one-shot cast into MFMA-fragment layouts.
//   xbf : x fragments for kA's B operand
//   w1f : W1 column fragments for kA's A operand (8 a-cols + 8 c-cols per hc)
//   w2f : W2 fragments for kB's B operand
// ---------------------------------------------------------------------------
__global__ __launch_bounds__(256) void kX(
    const float* __restrict__ x, const float* __restrict__ W1,
    const float* __restrict__ W2, uint4* __restrict__ xbf,
    uint4* __restrict__ w1f, uint4* __restrict__ w2f)
{
  const int u = blockIdx.x * 256 + threadIdx.x;
  if (u < 131072) {            // x frags: 16b x 16t x 8c x 64l
    const int l = u & 63, c = (u >> 6) & 7, t = (u >> 9) & 15, b = u >> 13;
    const int fr = l & 15, fq = l >> 4;
    const float* p = x + (size_t)((b * 16 + t) * 16 + fr) * 256 + c * 32 + fq * 8;
    float4 va = *(const float4*)p;
    float4 vb = *(const float4*)(p + 4);
    xbf[u] = make_uint4(pack2(va.x, va.y), pack2(va.z, va.w),
                        pack2(vb.x, vb.y), pack2(vb.z, vb.w));
  } else if (u < 139264) {     // W1 frags: 16hc x 8c x 64l
    const int u2 = u - 131072;
    const int l = u2 & 63, c = (u2 >> 6) & 7, hc = u2 >> 9;
    const int fr = l & 15, fq = l >> 4;
    const float* p = W1 + (size_t)((fr >= 8) ? 256 : 0) * 128 +
                     (size_t)(c * 32 + fq * 8) * 128 + hc * 8 + (fr & 7);
    float v[8];
#pragma unroll
    for (int j = 0; j < 8; ++j) v[j] = p[(size_t)j * 128];
    w1f[u2] = make_uint4(pack2(v[0], v[1]), pack2(v[2], v[3]),
                         pack2(v[4], v[5]), pack2(v[6], v[7]));
  } else if (u < 143360) {     // W2 frags: 16dg x 4c x 64l
    const int u3 = u - 139264;
    const int l = u3 & 63, c = (u3 >> 6) & 3, dg = u3 >> 8;
    const int fr = l & 15, fq = l >> 4;
    const float* p = W2 + (size_t)(c * 32 + fq * 8) * 256 + dg * 16 + fr;
    float v[8];
#pragma unroll
    for (int j = 0; j < 8; ++j) v[j] = p[(size_t)j * 256];
    w2f[u3] = make_uint4(pack2(v[0], v[1]), pack2(v[2], v[3]),
                         pack2(v[4], v[5]), pack2(v[6], v[7]));
  }
}

// ---------------------------------------------------------------------------
// kA (r8 structure; ONLY phase-2 inner loop changed to pk_add + folded-abs,
// 1.5 VALU/elem, bitwise-identical summation pairing to r8).
// Block (b, hc), 1024 thr = 16 waves.
// ---------------------------------------------------------------------------
__global__ __launch_bounds__(1024) void kA(
    const uint4* __restrict__ xbf, const uint4* __restrict__ w1f,
    const float* __restrict__ b1, uint4* __restrict__ mf)
{
  __shared__ float Cs[8][260];
  __shared__ float As[8][260];
  __shared__ float PB[8][260];

  const int tid = threadIdx.x, lane = tid & 63, wv = tid >> 6;  // wv 0..15
  const int b = blockIdx.x, hc = blockIdx.y;
  const int fr = lane & 15, fq = lane >> 4;

  FragU afr[8];
#pragma unroll
  for (int c = 0; c < 8; ++c) afr[c].q = w1f[(hc * 8 + c) * 64 + lane];

  float b1v[4];
#pragma unroll
  for (int g = 0; g < 4; ++g)
    b1v[g] = (fq >= 2) ? b1[hc * 8 + (fq - 2) * 4 + g] : 0.f;

  {  // phase 1: MFMA, wave = m-tile
    const int t = wv;
    f32x4 acc = {0.f, 0.f, 0.f, 0.f};
#pragma unroll
    for (int c = 0; c < 8; ++c) {
      FragU bfr;
      bfr.q = xbf[((size_t)(b * 16 + t) * 8 + c) * 64 + lane];
      acc = __builtin_amdgcn_mfma_f32_16x16x32_bf16(afr[c].h, bfr.h, acc, 0, 0, 0);
    }
    const int m = t * 16 + fr;
    if (fq < 2) {
#pragma unroll
      for (int g = 0; g < 4; ++g) As[fq * 4 + g][m] = acc[g];
    } else {
#pragma unroll
      for (int g = 0; g < 4; ++g) Cs[(fq - 2) * 4 + g][m] = acc[g] + b1v[g];
    }
  }
  __syncthreads();

  // phase 2: wave = (hp, kh); R=4 rows; broadcast ds_read_b128 of c.
  const int hp = wv & 7, kh = wv >> 3;
  const float a0 = As[hp][lane],       a1 = As[hp][64 + lane];
  const float a2 = As[hp][128 + lane], a3 = As[hp][192 + lane];

  float sumC = 0.f;
  if (kh == 0) {
    float4 s4 = *(const float4*)&Cs[hp][lane * 4];
    sumC = (s4.x + s4.y) + (s4.z + s4.w);
#pragma unroll
    for (int off = 32; off >= 1; off >>= 1) sumC += __shfl_xor(sumC, off, 64);
  }

  const f32x2 aa0 = {a0, a0}, aa1 = {a1, a1}, aa2 = {a2, a2}, aa3 = {a3, a3};
  float s0a = 0.f, s0b = 0.f, s1a = 0.f, s1b = 0.f;
  float s2a = 0.f, s2b = 0.f, s3a = 0.f, s3b = 0.f;
  const int u0 = kh * 32;

  // per 4 elems per row: 2 v_pk_add_f32 + 4 fabs-folded v_add_f32 = 1.5/elem.
  // sl accumulates c.x,c.z ; sh accumulates c.y,c.w  (same pairing as r8).
#define PROW(aa, sl, sh)                                                   \
  {                                                                        \
    f32x2 t0, t1;                                                          \
    asm("v_pk_add_f32 %0, %1, %2" : "=v"(t0) : "v"(aa), "v"(c01));         \
    asm("v_pk_add_f32 %0, %1, %2" : "=v"(t1) : "v"(aa), "v"(c23));         \
    sl += __builtin_fabsf(t0.x); sh += __builtin_fabsf(t0.y);              \
    sl += __builtin_fabsf(t1.x); sh += __builtin_fabsf(t1.y);              \
  }

#pragma unroll 8
  for (int u = 0; u < 32; ++u) {
    float4 c4 = *(const float4*)&Cs[hp][(u0 + u) * 4];  // uniform -> broadcast
    f32x2 c01 = {c4.x, c4.y}, c23 = {c4.z, c4.w};
    PROW(aa0, s0a, s0b)
    PROW(aa1, s1a, s1b)
    PROW(aa2, s2a, s2b)
    PROW(aa3, s3a, s3b)
  }
#undef PROW

  if (kh == 1) {
    PB[hp][lane]       = s0a + s0b;
    PB[hp][64 + lane]  = s1a + s1b;
    PB[hp][128 + lane] = s2a + s2b;
    PB[hp][192 + lane] = s3a + s3b;
  }
  __syncthreads();

  if (kh == 0) {
    As[hp][lane]       = (256.f * a0 + sumC + (s0a + s0b) + PB[hp][lane])       * (1.f / 512.f);
    As[hp][64 + lane]  = (256.f * a1 + sumC + (s1a + s1b) + PB[hp][64 + lane])  * (1.f / 512.f);
    As[hp][128 + lane] = (256.f * a2 + sumC + (s2a + s2b) + PB[hp][128 + lane]) * (1.f / 512.f);
    As[hp][192 + lane] = (256.f * a3 + sumC + (s3a + s3b) + PB[hp][192 + lane]) * (1.f / 512.f);
  }
  __syncthreads();

  // phase 3: pack row m=tid into kB fragment layout (r8-verbatim)
  if (tid < 256) {
    const int fr2 = tid & 15, T = tid >> 4;
    uint4 o = make_uint4(pack2(As[0][tid], As[1][tid]), pack2(As[2][tid], As[3][tid]),
                         pack2(As[4][tid], As[5][tid]), pack2(As[6][tid], As[7][tid]));
    mf[((size_t)(b * 16 + T) * 4 + (hc >> 2)) * 64 + (hc & 3) * 16 + fr2] = o;
  }
}

// ---------------------------------------------------------------------------
// kB (r8-verbatim): out[m][d] = mh@W2 + b2 + x. Grid (256,4) x 256 thr.
// ---------------------------------------------------------------------------
__global__ __launch_bounds__(256) void kB(
    const uint4* __restrict__ mf, const uint4* __restrict__ w2f,
    const float* __restrict__ b2, const float* __restrict__ x,
    float* __restrict__ out)
{
  const int tid = threadIdx.x, lane = tid & 63, wu = tid >> 6;
  const int mt = blockIdx.x;
  const int dg = blockIdx.y * 4 + wu;
  const int fr = lane & 15, fq = lane >> 4;

  f32x4 acc = {0.f, 0.f, 0.f, 0.f};
#pragma unroll
  for (int c = 0; c < 4; ++c) {
    FragU a, bb;
    a.q  = mf[((size_t)mt * 4 + c) * 64 + lane];
    bb.q = w2f[((size_t)dg * 4 + c) * 64 + lane];
    acc = __builtin_amdgcn_mfma_f32_16x16x32_bf16(a.h, bb.h, acc, 0, 0, 0);
  }

  const int d = dg * 16 + fr;
  const float bv = b2[d];
#pragma unroll
  for (int g = 0; g < 4; ++g) {
    const int m = mt * 16 + fq * 4 + g;
    const size_t o = (size_t)m * 256 + d;
    out[o] = acc[g] + bv + x[o];
  }
}

extern "C" void kernel_launch(void* const* d_in, const int* in_sizes, int n_in,
                              void* d_out, int out_size, void* d_ws, size_t ws_size,
                              hipStream_t stream) {
  const float* x  = (const float*)d_in[0];
  const float* W1 = (const float*)d_in[1];
  const float* b1 = (const float*)d_in[2];
  const float* W2 = (const float*)d_in[3];
  const float* b2 = (const float*)d_in[4];
  float* out = (float*)d_out;

  char* ws = (char*)d_ws;
  uint4* xbf = (uint4*)ws;                               // 131072 u = 2 MB
  uint4* w1f = (uint4*)(ws + (2u << 20));                // 8192 u = 128 KB
  uint4* w2f = (uint4*)(ws + (2u << 20) + (128u << 10)); // 4096 u = 64 KB
  uint4* mf  = (uint4*)(ws + (2u << 20) + (192u << 10)); // 65536 u = 1 MB

  kX<<<560, 256, 0, stream>>>(x, W1, W2, xbf, w1f, w2f);
  kA<<<dim3(16, 16), 1024, 0, stream>>>(xbf, w1f, b1, mf);
  kB<<<dim3(256, 4), 256, 0, stream>>>(mf, w2f, b2, x, out);
}

// Round 15
// 21.527 us; speedup vs baseline: 1.3549x; 1.1937x over previous
//
#include <hip/hip_runtime.h>

typedef __attribute__((ext_vector_type(8))) short bf16x8;
typedef __attribute__((ext_vector_type(4))) float f32x4;

union FragU { uint4 q; bf16x8 h; };

__device__ __forceinline__ unsigned short f2bf(float f) {
  unsigned u = __float_as_uint(f);
  u += 0x7FFFu + ((u >> 16) & 1u);   // RNE
  return (unsigned short)(u >> 16);
}
__device__ __forceinline__ unsigned pack2(float lo, float hi) {
  return (unsigned)f2bf(lo) | ((unsigned)f2bf(hi) << 16);
}

// ---------------------------------------------------------------------------
// kX (r8-verbatim): one-shot cast into MFMA-fragment layouts.
// ---------------------------------------------------------------------------
__global__ __launch_bounds__(256) void kX(
    const float* __restrict__ x, const float* __restrict__ W1,
    const float* __restrict__ W2, uint4* __restrict__ xbf,
    uint4* __restrict__ w1f, uint4* __restrict__ w2f)
{
  const int u = blockIdx.x * 256 + threadIdx.x;
  if (u < 131072) {            // x frags: 16b x 16t x 8c x 64l
    const int l = u & 63, c = (u >> 6) & 7, t = (u >> 9) & 15, b = u >> 13;
    const int fr = l & 15, fq = l >> 4;
    const float* p = x + (size_t)((b * 16 + t) * 16 + fr) * 256 + c * 32 + fq * 8;
    float4 va = *(const float4*)p;
    float4 vb = *(const float4*)(p + 4);
    xbf[u] = make_uint4(pack2(va.x, va.y), pack2(va.z, va.w),
                        pack2(vb.x, vb.y), pack2(vb.z, vb.w));
  } else if (u < 139264) {     // W1 frags: 16hc x 8c x 64l
    const int u2 = u - 131072;
    const int l = u2 & 63, c = (u2 >> 6) & 7, hc = u2 >> 9;
    const int fr = l & 15, fq = l >> 4;
    const float* p = W1 + (size_t)((fr >= 8) ? 256 : 0) * 128 +
                     (size_t)(c * 32 + fq * 8) * 128 + hc * 8 + (fr & 7);
    float v[8];
#pragma unroll
    for (int j = 0; j < 8; ++j) v[j] = p[(size_t)j * 128];
    w1f[u2] = make_uint4(pack2(v[0], v[1]), pack2(v[2], v[3]),
                         pack2(v[4], v[5]), pack2(v[6], v[7]));
  } else if (u < 143360) {     // W2 frags: 16dg x 4c x 64l
    const int u3 = u - 139264;
    const int l = u3 & 63, c = (u3 >> 6) & 3, dg = u3 >> 8;
    const int fr = l & 15, fq = l >> 4;
    const float* p = W2 + (size_t)(c * 32 + fq * 8) * 256 + dg * 16 + fr;
    float v[8];
#pragma unroll
    for (int j = 0; j < 8; ++j) v[j] = p[(size_t)j * 256];
    w2f[u3] = make_uint4(pack2(v[0], v[1]), pack2(v[2], v[3]),
                         pack2(v[4], v[5]), pack2(v[6], v[7]));
  }
}

// ---------------------------------------------------------------------------
// kA: phases 0/1/3 r14-verbatim.  NEW phase 1.5+2: sort-based pairwise.
//   1.5: wave wv<8 bitonic-sorts Cs[wv][0..255] in registers (4 elems/lane),
//        suffix-scan, store sortedC + sufS.
//   2:   16 waves x 64 lanes x 2 m: binary search idx = #{c <= -a} (8 LDS
//        probes), mh = ((256-idx)*a + sufS[idx]) / 256  [exact relu-sum].
// Block (b, hc), 1024 thr = 16 waves. Grid (16,16).
// ---------------------------------------------------------------------------
__global__ __launch_bounds__(1024) void kA(
    const uint4* __restrict__ xbf, const uint4* __restrict__ w1f,
    const float* __restrict__ b1, uint4* __restrict__ mf)
{
  __shared__ float Cs[8][260];
  __shared__ float As[8][260];      // a-values; overwritten in-place by mh
  __shared__ float sortedC[8][256];
  __shared__ float sufS[8][260];    // suffix sums; sufS[hp][256] = 0

  const int tid = threadIdx.x, lane = tid & 63, wv = tid >> 6;  // wv 0..15
  const int b = blockIdx.x, hc = blockIdx.y;
  const int fr = lane & 15, fq = lane >> 4;

  FragU afr[8];
#pragma unroll
  for (int c = 0; c < 8; ++c) afr[c].q = w1f[(hc * 8 + c) * 64 + lane];

  float b1v[4];
#pragma unroll
  for (int g = 0; g < 4; ++g)
    b1v[g] = (fq >= 2) ? b1[hc * 8 + (fq - 2) * 4 + g] : 0.f;

  {  // ---- phase 1: MFMA, wave = m-tile (r14-verbatim) ----
    const int t = wv;
    f32x4 acc = {0.f, 0.f, 0.f, 0.f};
#pragma unroll
    for (int c = 0; c < 8; ++c) {
      FragU bfr;
      bfr.q = xbf[((size_t)(b * 16 + t) * 8 + c) * 64 + lane];
      acc = __builtin_amdgcn_mfma_f32_16x16x32_bf16(afr[c].h, bfr.h, acc, 0, 0, 0);
    }
    const int m = t * 16 + fr;
    if (fq < 2) {
#pragma unroll
      for (int g = 0; g < 4; ++g) As[fq * 4 + g][m] = acc[g];
    } else {
#pragma unroll
      for (int g = 0; g < 4; ++g) Cs[(fq - 2) * 4 + g][m] = acc[g] + b1v[g];
    }
  }
  __syncthreads();

  // ---- phase 1.5: waves 0..7 sort Cs[wv] (bitonic, 4 regs/lane) ----
  if (wv < 8) {
    const int hp = wv;
    float v0 = Cs[hp][lane * 4 + 0], v1 = Cs[hp][lane * 4 + 1];
    float v2 = Cs[hp][lane * 4 + 2], v3 = Cs[hp][lane * 4 + 3];

#define CE2(X, Y, UP)                                     \
    {                                                     \
      float mn = fminf(X, Y), mx = fmaxf(X, Y);           \
      X = (UP) ? mn : mx;  Y = (UP) ? mx : mn;            \
    }
    // k=2
    CE2(v0, v1, true) CE2(v2, v3, false)
    // k=4
    {
      const bool up4 = (lane & 1) == 0;
      CE2(v0, v2, up4) CE2(v1, v3, up4)
      CE2(v0, v1, up4) CE2(v2, v3, up4)
    }
    // k = 8..256  (k4 = k/4)
#pragma unroll
    for (int k4 = 2; k4 <= 64; k4 <<= 1) {
      const bool up = (lane & k4) == 0;
#pragma unroll
      for (int j4 = k4 >> 1; j4 >= 1; j4 >>= 1) {   // cross-lane j = 4*j4
        const bool keepMin = (((lane & j4) == 0) == up);
#define CEX(V)                                            \
        {                                                 \
          float o = __shfl_xor(V, j4, 64);                \
          V = keepMin ? fminf(V, o) : fmaxf(V, o);        \
        }
        CEX(v0) CEX(v1) CEX(v2) CEX(v3)
#undef CEX
      }
      CE2(v0, v2, up) CE2(v1, v3, up)   // j=2
      CE2(v0, v1, up) CE2(v2, v3, up)   // j=1
    }
#undef CE2

    // suffix sums: T = sum over higher lanes, then in-lane suffix
    const float sl = (v0 + v1) + (v2 + v3);
    float inc = sl;
#pragma unroll
    for (int off = 1; off < 64; off <<= 1) {
      float t = __shfl_down(inc, off, 64);
      inc += (lane + off < 64) ? t : 0.f;
    }
    const float T = inc - sl;          // suffix strictly above this lane
    const float su3 = T + v3;
    const float su2 = su3 + v2;
    const float su1 = su2 + v1;
    const float su0 = su1 + v0;
    sortedC[hp][lane * 4 + 0] = v0;
    sortedC[hp][lane * 4 + 1] = v1;
    sortedC[hp][lane * 4 + 2] = v2;
    sortedC[hp][lane * 4 + 3] = v3;
    sufS[hp][lane * 4 + 0] = su0;
    sufS[hp][lane * 4 + 1] = su1;
    sufS[hp][lane * 4 + 2] = su2;
    sufS[hp][lane * 4 + 3] = su3;
    if (lane == 0) sufS[hp][256] = 0.f;
  }
  __syncthreads();

  // ---- phase 2: binary search; wave (hp = wv&7, half = wv>>3), 2 m each ----
  {
    const int hp = wv & 7, half = wv >> 3;
#pragma unroll
    for (int q = 0; q < 2; ++q) {
      const int m = half * 128 + q * 64 + lane;
      const float a = As[hp][m];
      const float t = -a;
      int idx = 0;
#pragma unroll
      for (int st = 128; st >= 1; st >>= 1)
        idx += (sortedC[hp][idx + st - 1] <= t) ? st : 0;
      const float cnt = (float)(256 - idx);
      const float S = sufS[hp][idx];
      As[hp][m] = (cnt * a + S) * (1.f / 256.f);
    }
  }
  __syncthreads();

  // ---- phase 3: pack row m=tid into kB fragment layout (r14-verbatim) ----
  if (tid < 256) {
    const int fr2 = tid & 15, T2 = tid >> 4;
    uint4 o = make_uint4(pack2(As[0][tid], As[1][tid]), pack2(As[2][tid], As[3][tid]),
                         pack2(As[4][tid], As[5][tid]), pack2(As[6][tid], As[7][tid]));
    mf[((size_t)(b * 16 + T2) * 4 + (hc >> 2)) * 64 + (hc & 3) * 16 + fr2] = o;
  }
}

// ---------------------------------------------------------------------------
// kB (r8-verbatim): out[m][d] = mh@W2 + b2 + x. Grid (256,4) x 256 thr.
// ---------------------------------------------------------------------------
__global__ __launch_bounds__(256) void kB(
    const uint4* __restrict__ mf, const uint4* __restrict__ w2f,
    const float* __restrict__ b2, const float* __restrict__ x,
    float* __restrict__ out)
{
  const int tid = threadIdx.x, lane = tid & 63, wu = tid >> 6;
  const int mt = blockIdx.x;
  const int dg = blockIdx.y * 4 + wu;
  const int fr = lane & 15, fq = lane >> 4;

  f32x4 acc = {0.f, 0.f, 0.f, 0.f};
#pragma unroll
  for (int c = 0; c < 4; ++c) {
    FragU a, bb;
    a.q  = mf[((size_t)mt * 4 + c) * 64 + lane];
    bb.q = w2f[((size_t)dg * 4 + c) * 64 + lane];
    acc = __builtin_amdgcn_mfma_f32_16x16x32_bf16(a.h, bb.h, acc, 0, 0, 0);
  }

  const int d = dg * 16 + fr;
  const float bv = b2[d];
#pragma unroll
  for (int g = 0; g < 4; ++g) {
    const int m = mt * 16 + fq * 4 + g;
    const size_t o = (size_t)m * 256 + d;
    out[o] = acc[g] + bv + x[o];
  }
}

extern "C" void kernel_launch(void* const* d_in, const int* in_sizes, int n_in,
                              void* d_out, int out_size, void* d_ws, size_t ws_size,
                              hipStream_t stream) {
  const float* x  = (const float*)d_in[0];
  const float* W1 = (const float*)d_in[1];
  const float* b1 = (const float*)d_in[2];
  const float* W2 = (const float*)d_in[3];
  const float* b2 = (const float*)d_in[4];
  float* out = (float*)d_out;

  char* ws = (char*)d_ws;
  uint4* xbf = (uint4*)ws;                               // 131072 u = 2 MB
  uint4* w1f = (uint4*)(ws + (2u << 20));                // 8192 u = 128 KB
  uint4* w2f = (uint4*)(ws + (2u << 20) + (128u << 10)); // 4096 u = 64 KB
  uint4* mf  = (uint4*)(ws + (2u << 20) + (192u << 10)); // 65536 u = 1 MB

  kX<<<560, 256, 0, stream>>>(x, W1, W2, xbf, w1f, w2f);
  kA<<<dim3(16, 16), 1024, 0, stream>>>(xbf, w1f, b1, mf);
  kB<<<dim3(256, 4), 256, 0, stream>>>(mf, w2f, b2, x, out);
}